// Round 8
// baseline (220.175 us; speedup 1.0000x reference)
//
#include <hip/hip_runtime.h>
#include <hip/hip_bf16.h>

#define B_  2
#define S_  2048
#define D_  1024
#define H_  16
#define HD_ 64

typedef __attribute__((ext_vector_type(8))) short short8;
typedef __attribute__((ext_vector_type(4))) float f32x4;

__device__ __forceinline__ unsigned short f2b(float f) {
    __hip_bfloat16 h = __float2bfloat16(f);
    unsigned short u;
    __builtin_memcpy(&u, &h, 2);
    return u;
}

// raw hardware exp2: v_exp_f32 computes 2^x in one TRANS op (scores bounded
// after log2e fold; no denormal guard needed — round-4/5 verified).
__device__ __forceinline__ float exp2_raw(float x) {
    float r;
    asm("v_exp_f32 %0, %1" : "=v"(r) : "v"(x));
    return r;
}

// packed f32x2 -> bf16x2 in ONE instruction (lo -> [15:0], hi -> [31:16]).
__device__ __forceinline__ unsigned int cvt_pk_bf16(float lo, float hi) {
    unsigned int r;
    asm("v_cvt_pk_bf16_f32 %0, %1, %2" : "=v"(r) : "v"(lo), "v"(hi));
    return r;
}

// async global->LDS, 16B per lane. LDS dest is wave-uniform base + lane*16.
typedef __attribute__((address_space(1))) const unsigned int g_u32;
typedef __attribute__((address_space(3))) unsigned int l_u32;
__device__ __forceinline__ void gload_lds16(const void* g, void* l) {
    __builtin_amdgcn_global_load_lds((g_u32*)g, (l_u32*)l, 16, 0, 0);
}

// ---------------------------------------------------------------------------
// Kernel 0: fp32 -> bf16 conversion for x, Wq, Wk, Wv, Wo into workspace.
// ---------------------------------------------------------------------------
__global__ __launch_bounds__(256) void convert_kernel(
    const float* __restrict__ x,  const float* __restrict__ Wq,
    const float* __restrict__ Wk, const float* __restrict__ Wv,
    const float* __restrict__ Wo, unsigned short* __restrict__ dst)
{
    const long long i4 = blockIdx.x * 256 + threadIdx.x;   // 0 .. 2M-1
    const long long e  = i4 * 4;
    const long long M1 = 1048576LL;
    const float* src;
    if      (e < 4 * M1) src = x  + e;
    else if (e < 5 * M1) src = Wq + (e - 4 * M1);
    else if (e < 6 * M1) src = Wk + (e - 5 * M1);
    else if (e < 7 * M1) src = Wv + (e - 6 * M1);
    else                 src = Wo + (e - 7 * M1);
    float4 v = *(const float4*)src;
    unsigned long long pk = (unsigned long long)f2b(v.x)
                          | ((unsigned long long)f2b(v.y) << 16)
                          | ((unsigned long long)f2b(v.z) << 32)
                          | ((unsigned long long)f2b(v.w) << 48);
    *(unsigned long long*)&dst[e] = pk;
}

// ---------------------------------------------------------------------------
// Kernel 1: QKV projection, 128x128 tile, BK=32, double-buffered gload_lds
// prefetch (round-7 verified). Linear 64B LDS rows = bank floor, no swizzle.
// Q (scaled 1/8 * log2e), K -> [B][H][S][HD], V -> [B][H][HD][S]
// ---------------------------------------------------------------------------
__global__ __launch_bounds__(256) void qkv_proj_kernel(
    const unsigned short* __restrict__ x,
    const unsigned short* __restrict__ Wq,
    const unsigned short* __restrict__ Wk,
    const unsigned short* __restrict__ Wv,
    unsigned short* __restrict__ q_ws,
    unsigned short* __restrict__ k_ws,
    unsigned short* __restrict__ vT_ws)
{
    __shared__ unsigned short a_lds[2][128 * 32];
    __shared__ unsigned short b_lds[2][128 * 32];

    const int m0 = blockIdx.x * 128;
    const int n0 = blockIdx.y * 128;
    const int which = blockIdx.z;
    const unsigned short* W = (which == 0) ? Wq : (which == 1) ? Wk : Wv;

    const int tid  = threadIdx.x;
    const int wave = tid >> 6;
    const int lane = tid & 63;
    const int l15  = lane & 15;
    const int quad = lane >> 4;
    const int wm = (wave & 1) * 64;
    const int wn = (wave >> 1) * 64;

    const int srow = tid >> 2;          // 0..63
    const int scol = (tid & 3) * 8;     // shorts
    const int soff = tid * 8;           // LDS shorts

    f32x4 acc[4][4];
    #pragma unroll
    for (int sm = 0; sm < 4; ++sm)
        #pragma unroll
        for (int sn = 0; sn < 4; ++sn)
            #pragma unroll
            for (int r = 0; r < 4; ++r) acc[sm][sn][r] = 0.f;

    #pragma unroll
    for (int p = 0; p < 2; ++p) {
        gload_lds16(&x[(m0 + srow + p * 64) * D_ + scol], &a_lds[0][p * 2048 + soff]);
        gload_lds16(&W[(n0 + srow + p * 64) * D_ + scol], &b_lds[0][p * 2048 + soff]);
    }
    __syncthreads();

    for (int t = 0; t < 32; ++t) {
        const int cur = t & 1;
        if (t < 31) {
            const int kk = (t + 1) * 32;
            #pragma unroll
            for (int p = 0; p < 2; ++p) {
                gload_lds16(&x[(m0 + srow + p * 64) * D_ + kk + scol],
                            &a_lds[cur ^ 1][p * 2048 + soff]);
                gload_lds16(&W[(n0 + srow + p * 64) * D_ + kk + scol],
                            &b_lds[cur ^ 1][p * 2048 + soff]);
            }
        }
        short8 af[4], bf[4];
        #pragma unroll
        for (int s = 0; s < 4; ++s) {
            af[s] = *(const short8*)&a_lds[cur][(wm + s * 16 + l15) * 32 + quad * 8];
            bf[s] = *(const short8*)&b_lds[cur][(wn + s * 16 + l15) * 32 + quad * 8];
        }
        #pragma unroll
        for (int sm = 0; sm < 4; ++sm)
            #pragma unroll
            for (int sn = 0; sn < 4; ++sn)
                acc[sm][sn] = __builtin_amdgcn_mfma_f32_16x16x32_bf16(
                    af[sm], bf[sn], acc[sm][sn], 0, 0, 0);
        __syncthreads();
    }

    #pragma unroll
    for (int sm = 0; sm < 4; ++sm) {
        #pragma unroll
        for (int sn = 0; sn < 4; ++sn) {
            const int n  = n0 + wn + sn * 16 + l15;
            const int h  = n >> 6;
            const int hd = n & 63;
            const int mbase = m0 + wm + sm * 16 + quad * 4;
            const int b     = mbase >> 11;
            const int sbase = mbase & 2047;
            if (which == 2) {
                unsigned long long pk =
                      (unsigned long long)cvt_pk_bf16(acc[sm][sn][0], acc[sm][sn][1])
                    | ((unsigned long long)cvt_pk_bf16(acc[sm][sn][2], acc[sm][sn][3]) << 32);
                *(unsigned long long*)&vT_ws[((b * H_ + h) * HD_ + hd) * S_ + sbase] = pk;
            } else if (which == 0) {
                #pragma unroll
                for (int r = 0; r < 4; ++r)
                    q_ws[((b * H_ + h) * S_ + (sbase + r)) * HD_ + hd] =
                        f2b(acc[sm][sn][r] * (0.125f * 1.44269504f));
            } else {
                #pragma unroll
                for (int r = 0; r < 4; ++r)
                    k_ws[((b * H_ + h) * S_ + (sbase + r)) * HD_ + hd] =
                        f2b(acc[sm][sn][r]);
            }
        }
    }
}

// ---------------------------------------------------------------------------
// Kernel 2: causal flash attention — LDS-FREE, barrier-free, 1 wave/block.
//   K/V for a (b,h) is L2-resident (512KB; 4 bh per XCD = 2MB hot set via
//   bh-keyed XCD mapping), and K rows / V^T rows are 16B-contiguous in
//   global -> MFMA fragments load DIRECT from global (coalesced dwordx4),
//   eliminating staging, 16 ds_reads and 2 barriers per tile. One wave
//   handles 32 q rows (two 16-row groups sharing K-fragment loads -> L2
//   traffic halved vs 16-row waves). Template-static diagonal tile skips
//   the fully-masked half for even qsub (rule 20: all indices static).
// ---------------------------------------------------------------------------
template<int FMAX, int CMAX, bool MASK>
__device__ __forceinline__ void attn_tile(
    const int k0,
    const unsigned short* __restrict__ Kh,
    const unsigned short* __restrict__ Vt,
    const short8* aq0, const short8* aq1,
    f32x4* o0, f32x4* o1, float& l0, float& l1,
    const int l15, const int quad, const int qg0, const int qg1,
    const int src0, const int src1, const int sel)
{
    // K fragments: 16B/lane, wave covers the full 16x64 row-panel (coalesced)
    short8 ak[FMAX][2];
    #pragma unroll
    for (int f = 0; f < FMAX; ++f)
        #pragma unroll
        for (int kc = 0; kc < 2; ++kc)
            ak[f][kc] = *(const short8*)&Kh[(k0 + f * 16 + l15) * HD_ + kc * 32 + quad * 8];
    // V^T fragments issued early: latency hides under QK + softmax
    short8 av[CMAX][4];
    #pragma unroll
    for (int c = 0; c < CMAX; ++c)
        #pragma unroll
        for (int f = 0; f < 4; ++f)
            av[c][f] = *(const short8*)&Vt[(f * 16 + l15) * S_ + k0 + c * 32 + quad * 8];

    // S^T[key][q] for both q-groups (K fragments shared)
    f32x4 sc0[FMAX], sc1[FMAX];
    #pragma unroll
    for (int f = 0; f < FMAX; ++f)
        #pragma unroll
        for (int r = 0; r < 4; ++r) { sc0[f][r] = 0.f; sc1[f][r] = 0.f; }
    #pragma unroll
    for (int f = 0; f < FMAX; ++f)
        #pragma unroll
        for (int kc = 0; kc < 2; ++kc) {
            sc0[f] = __builtin_amdgcn_mfma_f32_16x16x32_bf16(ak[f][kc], aq0[kc], sc0[f], 0, 0, 0);
            sc1[f] = __builtin_amdgcn_mfma_f32_16x16x32_bf16(ak[f][kc], aq1[kc], sc1[f], 0, 0, 0);
        }

    // p = 2^score, causal mask on the diagonal tile
    float p0[FMAX][4], p1[FMAX][4];
    #pragma unroll
    for (int f = 0; f < FMAX; ++f)
        #pragma unroll
        for (int r = 0; r < 4; ++r) {
            float v0 = exp2_raw(sc0[f][r]);
            float v1 = exp2_raw(sc1[f][r]);
            if (MASK) {
                const int key = k0 + f * 16 + quad * 4 + r;
                v0 = (key > qg0) ? 0.f : v0;
                v1 = (key > qg1) ? 0.f : v1;
            }
            p0[f][r] = v0; l0 += v0;
            p1[f][r] = v1; l1 += v1;
        }

    unsigned int pd0[FMAX][2], pd1[FMAX][2];
    #pragma unroll
    for (int f = 0; f < FMAX; ++f) {
        pd0[f][0] = cvt_pk_bf16(p0[f][0], p0[f][1]);
        pd0[f][1] = cvt_pk_bf16(p0[f][2], p0[f][3]);
        pd1[f][0] = cvt_pk_bf16(p1[f][0], p1[f][1]);
        pd1[f][1] = cvt_pk_bf16(p1[f][2], p1[f][3]);
    }

    // P^T B-fragment: shuffle both f-candidates, select on destination
    #pragma unroll
    for (int c = 0; c < CMAX; ++c) {
        union { int i[4]; short8 s; } u20, u21;
        {
            const int a0 = __shfl((int)pd0[c * 2][0],     src0, 64);
            const int a1 = __shfl((int)pd0[c * 2][1],     src0, 64);
            const int a2 = __shfl((int)pd0[c * 2][0],     src1, 64);
            const int a3 = __shfl((int)pd0[c * 2][1],     src1, 64);
            const int b0 = __shfl((int)pd0[c * 2 + 1][0], src0, 64);
            const int b1 = __shfl((int)pd0[c * 2 + 1][1], src0, 64);
            const int b2 = __shfl((int)pd0[c * 2 + 1][0], src1, 64);
            const int b3 = __shfl((int)pd0[c * 2 + 1][1], src1, 64);
            u20.i[0] = sel ? b0 : a0;  u20.i[1] = sel ? b1 : a1;
            u20.i[2] = sel ? b2 : a2;  u20.i[3] = sel ? b3 : a3;
        }
        {
            const int a0 = __shfl((int)pd1[c * 2][0],     src0, 64);
            const int a1 = __shfl((int)pd1[c * 2][1],     src0, 64);
            const int a2 = __shfl((int)pd1[c * 2][0],     src1, 64);
            const int a3 = __shfl((int)pd1[c * 2][1],     src1, 64);
            const int b0 = __shfl((int)pd1[c * 2 + 1][0], src0, 64);
            const int b1 = __shfl((int)pd1[c * 2 + 1][1], src0, 64);
            const int b2 = __shfl((int)pd1[c * 2 + 1][0], src1, 64);
            const int b3 = __shfl((int)pd1[c * 2 + 1][1], src1, 64);
            u21.i[0] = sel ? b0 : a0;  u21.i[1] = sel ? b1 : a1;
            u21.i[2] = sel ? b2 : a2;  u21.i[3] = sel ? b3 : a3;
        }
        #pragma unroll
        for (int f = 0; f < 4; ++f) {
            o0[f] = __builtin_amdgcn_mfma_f32_16x16x32_bf16(av[c][f], u20.s, o0[f], 0, 0, 0);
            o1[f] = __builtin_amdgcn_mfma_f32_16x16x32_bf16(av[c][f], u21.s, o1[f], 0, 0, 0);
        }
    }
}

__global__ __launch_bounds__(64) void attn_kernel(
    const unsigned short* __restrict__ q_ws,
    const unsigned short* __restrict__ k_ws,
    const unsigned short* __restrict__ vT_ws,
    unsigned short* __restrict__ ctx_ws)   // [B*S][D], col = h*64+hd
{
    const int wgid = blockIdx.x;            // 0..2047
    const int bh   = wgid & 31;             // wgid%8 = bh%8 -> bh keyed to XCD
    const int qsub = 63 - (wgid >> 5);      // heavy q-blocks dispatched first

    const int lane = threadIdx.x;           // 0..63
    const int l15  = lane & 15;
    const int quad = lane >> 4;

    const unsigned short* Qh = q_ws + bh * (S_ * HD_);
    const unsigned short* Kh = k_ws + bh * (S_ * HD_);
    const unsigned short* Vt = vT_ws + bh * (HD_ * S_);
    const int b = bh >> 4;
    const int h = bh & 15;

    const int src0 = l15 + 32 * (quad & 1);
    const int src1 = src0 + 16;
    const int sel  = quad >> 1;

    const int q0  = qsub * 32;
    const int qg0 = q0 + l15;          // group-0 q row
    const int qg1 = q0 + 16 + l15;     // group-1 q row

    short8 aq0[2], aq1[2];
    aq0[0] = *(const short8*)&Qh[qg0 * HD_ + quad * 8];
    aq0[1] = *(const short8*)&Qh[qg0 * HD_ + 32 + quad * 8];
    aq1[0] = *(const short8*)&Qh[qg1 * HD_ + quad * 8];
    aq1[1] = *(const short8*)&Qh[qg1 * HD_ + 32 + quad * 8];

    float l0 = 0.f, l1 = 0.f;
    f32x4 o0[4], o1[4];
    #pragma unroll
    for (int f = 0; f < 4; ++f)
        #pragma unroll
        for (int r = 0; r < 4; ++r) { o0[f][r] = 0.f; o1[f][r] = 0.f; }

    const int NT = (qsub >> 1) + 1;    // causal tile count for rows q0..q0+31

    for (int kt = 0; kt < NT - 1; ++kt)
        attn_tile<4, 2, false>(kt * 64, Kh, Vt, aq0, aq1, o0, o1, l0, l1,
                               l15, quad, qg0, qg1, src0, src1, sel);
    const int k0 = (NT - 1) * 64;
    if (qsub & 1)   // odd: lower half-tile unmasked, upper triangular
        attn_tile<4, 2, true>(k0, Kh, Vt, aq0, aq1, o0, o1, l0, l1,
                              l15, quad, qg0, qg1, src0, src1, sel);
    else            // even: keys k0+32.. fully masked -> skip (FMAX=2, CMAX=1)
        attn_tile<2, 1, true>(k0, Kh, Vt, aq0, aq1, o0, o1, l0, l1,
                              l15, quad, qg0, qg1, src0, src1, sel);

    // l reduction across quads (key dim) + ctx write per group
    l0 += __shfl_xor(l0, 16, 64);
    l0 += __shfl_xor(l0, 32, 64);
    l1 += __shfl_xor(l1, 16, 64);
    l1 += __shfl_xor(l1, 32, 64);
    const float inv0 = 1.0f / l0;
    const float inv1 = 1.0f / l1;

    #pragma unroll
    for (int f = 0; f < 4; ++f) {
        unsigned long long pk0 =
              (unsigned long long)cvt_pk_bf16(o0[f][0] * inv0, o0[f][1] * inv0)
            | ((unsigned long long)cvt_pk_bf16(o0[f][2] * inv0, o0[f][3] * inv0) << 32);
        *(unsigned long long*)&ctx_ws[(b * S_ + qg0) * D_ + h * 64 + f * 16 + quad * 4] = pk0;
        unsigned long long pk1 =
              (unsigned long long)cvt_pk_bf16(o1[f][0] * inv1, o1[f][1] * inv1)
            | ((unsigned long long)cvt_pk_bf16(o1[f][2] * inv1, o1[f][3] * inv1) << 32);
        *(unsigned long long*)&ctx_ws[(b * S_ + qg1) * D_ + h * 64 + f * 16 + quad * 4] = pk1;
    }
}

// ---------------------------------------------------------------------------
// Kernel 3: output projection + bias, 128x128 tile, BK=32 dbuf prefetch.
// ---------------------------------------------------------------------------
__global__ __launch_bounds__(256) void out_proj_kernel(
    const unsigned short* __restrict__ ctx,
    const unsigned short* __restrict__ Wo,
    const float* __restrict__ bo,
    float* __restrict__ out)
{
    __shared__ unsigned short a_lds[2][128 * 32];
    __shared__ unsigned short b_lds[2][128 * 32];

    const int m0 = blockIdx.x * 128;
    const int n0 = blockIdx.y * 128;

    const int tid  = threadIdx.x;
    const int wave = tid >> 6;
    const int lane = tid & 63;
    const int l15  = lane & 15;
    const int quad = lane >> 4;
    const int wm = (wave & 1) * 64;
    const int wn = (wave >> 1) * 64;

    const int srow = tid >> 2;
    const int scol = (tid & 3) * 8;
    const int soff = tid * 8;

    f32x4 acc[4][4];
    #pragma unroll
    for (int sm = 0; sm < 4; ++sm)
        #pragma unroll
        for (int sn = 0; sn < 4; ++sn)
            #pragma unroll
            for (int r = 0; r < 4; ++r) acc[sm][sn][r] = 0.f;

    #pragma unroll
    for (int p = 0; p < 2; ++p) {
        gload_lds16(&ctx[(m0 + srow + p * 64) * D_ + scol], &a_lds[0][p * 2048 + soff]);
        gload_lds16(&Wo[(n0 + srow + p * 64) * D_ + scol],  &b_lds[0][p * 2048 + soff]);
    }
    __syncthreads();

    for (int t = 0; t < 32; ++t) {
        const int cur = t & 1;
        if (t < 31) {
            const int kk = (t + 1) * 32;
            #pragma unroll
            for (int p = 0; p < 2; ++p) {
                gload_lds16(&ctx[(m0 + srow + p * 64) * D_ + kk + scol],
                            &a_lds[cur ^ 1][p * 2048 + soff]);
                gload_lds16(&Wo[(n0 + srow + p * 64) * D_ + kk + scol],
                            &b_lds[cur ^ 1][p * 2048 + soff]);
            }
        }
        short8 af[4], bf[4];
        #pragma unroll
        for (int s = 0; s < 4; ++s) {
            af[s] = *(const short8*)&a_lds[cur][(wm + s * 16 + l15) * 32 + quad * 8];
            bf[s] = *(const short8*)&b_lds[cur][(wn + s * 16 + l15) * 32 + quad * 8];
        }
        #pragma unroll
        for (int sm = 0; sm < 4; ++sm)
            #pragma unroll
            for (int sn = 0; sn < 4; ++sn)
                acc[sm][sn] = __builtin_amdgcn_mfma_f32_16x16x32_bf16(
                    af[sm], bf[sn], acc[sm][sn], 0, 0, 0);
        __syncthreads();
    }

    #pragma unroll
    for (int sm = 0; sm < 4; ++sm) {
        #pragma unroll
        for (int sn = 0; sn < 4; ++sn) {
            const int n = n0 + wn + sn * 16 + l15;
            const float bias = bo[n];
            const int mbase = m0 + wm + sm * 16 + quad * 4;
            #pragma unroll
            for (int r = 0; r < 4; ++r)
                out[(mbase + r) * D_ + n] = acc[sm][sn][r] + bias;
        }
    }
}

// ---------------------------------------------------------------------------
extern "C" void kernel_launch(void* const* d_in, const int* in_sizes, int n_in,
                              void* d_out, int out_size, void* d_ws, size_t ws_size,
                              hipStream_t stream) {
    const float* x  = (const float*)d_in[0];
    const float* Wq = (const float*)d_in[1];
    const float* Wk = (const float*)d_in[2];
    const float* Wv = (const float*)d_in[3];
    const float* Wo = (const float*)d_in[4];
    const float* bo = (const float*)d_in[5];
    float* out = (float*)d_out;

    const size_t M1 = 1048576;           // 1M elements
    const size_t SZ = 4 * M1;            // B*S*D = 4M elements

    unsigned short* xb  = (unsigned short*)d_ws;     // 4M
    unsigned short* wqb = xb  + SZ;                  // 1M
    unsigned short* wkb = wqb + M1;                  // 1M
    unsigned short* wvb = wkb + M1;                  // 1M
    unsigned short* wob = wvb + M1;                  // 1M
    unsigned short* q_ws   = wob + M1;               // 4M
    unsigned short* k_ws   = q_ws + SZ;              // 4M
    unsigned short* vT_ws  = k_ws + SZ;              // 4M
    unsigned short* ctx_ws = vT_ws + SZ;             // 4M  (total 24M u16 = 48MB)

    convert_kernel<<<dim3(8192), 256, 0, stream>>>(x, Wq, Wk, Wv, Wo, xb);
    qkv_proj_kernel<<<dim3(32, 8, 3), 256, 0, stream>>>(xb, wqb, wkb, wvb, q_ws, k_ws, vT_ws);
    attn_kernel<<<dim3(2048), 64, 0, stream>>>(q_ws, k_ws, vT_ws, ctx_ws);
    out_proj_kernel<<<dim3(32, 8), 256, 0, stream>>>(ctx_ws, wob, bo, out);
}